// Round 7
// baseline (2278.509 us; speedup 1.0000x reference)
//
#include <hip/hip_runtime.h>
#include <math.h>

// BiometricLSTM: 2-layer LSTM, B=512, T=2048, I=3, H=64, fp32. Output = final h of layer 2 (B,64).
//
// R7: R6 went 5.04->2.26 ms (2 blocks/CU latency hiding) but VGPR_Count fell
// 256->120: LDS shrank to 36 KB -> 4 blocks fit by LDS -> allocator targeted
// 4 waves/SIMD -> arch cap 512/4=128 -> the 192 weight floats/thread moved to
// AGPRs -> ~160 v_accvgpr_read/iter of pure VALU overhead (VALUBusy 57% at
// 2642 cyc/iter implies ~376 VALU instrs/thread-iter vs ~215 in source).
// Allocator law (fits R1-R6): arch cap = 512/(blocks_fit_by_LDS*waves_per_block/4).
// Fix: pad LDS > 160/3 = 53.3 KB so only 2 blocks fit -> cap 256 -> weights in
// arch VGPRs (R5 proved this exact config allocates 256). Grid stays 512 = 2
// blocks/CU. Only the LDS pad differs from R6.
//
//   512 blocks x 256 threads (4 waves), 1 seq/block, 2 blocks/CU.
//   phase 1 (all threads): L0 gate j (step it) + L1 gate j (step it-1),
//     activation in-phase (gate class == wave index, uniform branch).
//   phase 2 (threads 0-127): wave0 = L0 state update, wave1 = L1 state update;
//     c_state in registers. 2 barriers/iter. Layers pipelined with 1-step lag.

constexpr int TT = 2048;

__device__ __forceinline__ float fast_sigmoid(float x) {
    return 1.0f / (1.0f + __expf(-x));
}

// overflow-safe tanh: c can reach O(100s); exp(-2|x|) underflows harmlessly to 0 -> +/-1
__device__ __forceinline__ float fast_tanh(float x) {
    float ax = fabsf(x);
    float t  = __expf(-2.0f * ax);
    return copysignf((1.0f - t) / (1.0f + t), x);
}

__global__ __launch_bounds__(256) void lstm2_fused(
    const float* __restrict__ x,
    const float* __restrict__ Wih0, const float* __restrict__ Whh0,
    const float* __restrict__ bih0, const float* __restrict__ bhh0,
    const float* __restrict__ Wih1, const float* __restrict__ Whh1,
    const float* __restrict__ bih1, const float* __restrict__ bhh1,
    float* __restrict__ out)
{
    // x stride-4 (one ds_read_b128/iter) + 5120-float pad: total LDS ~56.8 KB
    // > 53.3 KB so only 2 blocks/CU fit by LDS -> allocator targets 2 waves/SIMD
    // -> 256 arch VGPRs -> 192 weight floats stay in arch VGPRs (no AGPR moves).
    // Pad is inside a used array so it can't be dropped; grid uses 2 blocks/CU.
    __shared__ __align__(16) float xs4[TT * 4 + 4 + 5120];   // ~52.3 KB
    __shared__ __align__(16) float h1buf[2][64];        // [parity][k]
    __shared__ __align__(16) float h2buf[2][64];
    __shared__ __align__(16) float gbuf[2][256];        // [layer][gate], activated

    const int j = threadIdx.x;            // gate index 0..255

    // ---- preload x: global (T,3) packed -> LDS stride 4 (w-slot unused) ----
    {
        const float* xg = x + (size_t)blockIdx.x * (TT * 3);
        for (int idx = j; idx < TT * 3; idx += 256) {
            int t = idx / 3;              // magic-mul, no HW divide
            int c = idx - 3 * t;
            xs4[t * 4 + c] = xg[idx];
        }
        if (j < 4) xs4[TT * 4 + j] = 0.0f;
    }
    // ---- zero h double-buffers ----
    if (j < 128)       ((float*)h1buf)[j] = 0.0f;
    else               ((float*)h2buf)[j - 128] = 0.0f;

    // ---- thread j's weights: gate j of both layers (192+5 floats, registers) ----
    float wA[64], wB[64], wC[64];   // Whh0 row j | Wih1 row j | Whh1 row j
    {
        const float4* a = (const float4*)(Whh0 + j * 64);
        const float4* b = (const float4*)(Wih1 + j * 64);
        const float4* c = (const float4*)(Whh1 + j * 64);
        #pragma unroll
        for (int k = 0; k < 16; ++k) {
            float4 va = a[k];
            wA[4*k+0] = va.x; wA[4*k+1] = va.y; wA[4*k+2] = va.z; wA[4*k+3] = va.w;
            float4 vb = b[k];
            wB[4*k+0] = vb.x; wB[4*k+1] = vb.y; wB[4*k+2] = vb.z; wB[4*k+3] = vb.w;
            float4 vc = c[k];
            wC[4*k+0] = vc.x; wC[4*k+1] = vc.y; wC[4*k+2] = vc.z; wC[4*k+3] = vc.w;
        }
    }
    const float wx0 = Wih0[j*3+0], wx1 = Wih0[j*3+1], wx2 = Wih0[j*3+2];
    const float bias0 = bih0[j] + bhh0[j];
    const float bias1 = bih1[j] + bhh1[j];

    const int cls = j >> 6;               // 0:i 1:f 2:g 3:o (== wave index, uniform)
    const int uL  = (j >> 6) & 1;         // phase-2: wave0 -> L0, wave1 -> L1
    const int uj  = j & 63;
    float c_state = 0.0f;

    __syncthreads();

    // iter it: L0 computes step it (valid it<TT); L1 computes step it-1 (valid it>=1).
    // Edge iters compute garbage unconditionally on zeroed/in-bounds inputs; only
    // state updates / stores are guarded.
    for (int it = 0; it <= TT; ++it) {
        const int cur  = it & 1;
        const int prev = cur ^ 1;

        // ---------------- phase 1: gate dot-products ----------------
        const float4* h1p = (const float4*)h1buf[prev];   // h1[it-1] (broadcast)
        const float4* h2p = (const float4*)h2buf[cur];    // h2[it-2]

        float Aa=0.f, Ab=0.f;   // L0:  Whh0[j] . h1
        float Ia=0.f, Ib=0.f;   // L1:  Wih1[j] . h1
        float Ha=0.f, Hb=0.f;   // L1:  Whh1[j] . h2
        #pragma unroll
        for (int k = 0; k < 16; ++k) {
            float4 p = h1p[k];
            float4 r = h2p[k];
            Aa = fmaf(wA[4*k+0], p.x, Aa); Ab = fmaf(wA[4*k+1], p.y, Ab);
            Aa = fmaf(wA[4*k+2], p.z, Aa); Ab = fmaf(wA[4*k+3], p.w, Ab);
            Ia = fmaf(wB[4*k+0], p.x, Ia); Ib = fmaf(wB[4*k+1], p.y, Ib);
            Ia = fmaf(wB[4*k+2], p.z, Ia); Ib = fmaf(wB[4*k+3], p.w, Ib);
            Ha = fmaf(wC[4*k+0], r.x, Ha); Hb = fmaf(wC[4*k+1], r.y, Hb);
            Ha = fmaf(wC[4*k+2], r.z, Ha); Hb = fmaf(wC[4*k+3], r.w, Hb);
        }
        float4 xv = ((const float4*)xs4)[it];
        float g0 = bias0 + (Aa + Ab) + wx0*xv.x + wx1*xv.y + wx2*xv.z;
        float g1 = bias1 + (Ia + Ib) + (Ha + Hb);
        if (cls == 2) { g0 = fast_tanh(g0);    g1 = fast_tanh(g1); }
        else          { g0 = fast_sigmoid(g0); g1 = fast_sigmoid(g1); }
        gbuf[0][j] = g0;
        gbuf[1][j] = g1;
        __syncthreads();

        // ---------------- phase 2: state updates (threads 0-127) ----------------
        if (j < 128) {
            if (uL == 0) {
                if (it < TT) {
                    float iv = gbuf[0][      uj];
                    float fv = gbuf[0][ 64 + uj];
                    float gv = gbuf[0][128 + uj];
                    float ov = gbuf[0][192 + uj];
                    c_state = fmaf(fv, c_state, iv * gv);
                    h1buf[cur][uj] = ov * fast_tanh(c_state);       // h1[it]
                }
            } else {
                if (it >= 1) {
                    float iv = gbuf[1][      uj];
                    float fv = gbuf[1][ 64 + uj];
                    float gv = gbuf[1][128 + uj];
                    float ov = gbuf[1][192 + uj];
                    c_state = fmaf(fv, c_state, iv * gv);
                    float hv = ov * fast_tanh(c_state);
                    h2buf[prev][uj] = hv;                           // h2[it-1]
                    if (it == TT)
                        out[(size_t)blockIdx.x * 64 + uj] = hv;
                }
            }
        }
        __syncthreads();
    }
}

extern "C" void kernel_launch(void* const* d_in, const int* in_sizes, int n_in,
                              void* d_out, int out_size, void* d_ws, size_t ws_size,
                              hipStream_t stream) {
    const float* x    = (const float*)d_in[0];
    const float* Wih0 = (const float*)d_in[1];
    const float* Whh0 = (const float*)d_in[2];
    const float* bih0 = (const float*)d_in[3];
    const float* bhh0 = (const float*)d_in[4];
    const float* Wih1 = (const float*)d_in[5];
    const float* Whh1 = (const float*)d_in[6];
    const float* bih1 = (const float*)d_in[7];
    const float* bhh1 = (const float*)d_in[8];
    float* out = (float*)d_out;

    // 512 sequences, 1 per block -> 512 blocks = 2 blocks/CU (2 waves/SIMD);
    // 256 threads (4 waves) + >53.3 KB LDS -> 256 arch-VGPR budget (no AGPR moves).
    lstm2_fused<<<512, 256, 0, stream>>>(x, Wih0, Whh0, bih0, bhh0,
                                         Wih1, Whh1, bih1, bhh1, out);
}

// Round 8
// 1860.041 us; speedup vs baseline: 1.2250x; 1.2250x over previous
//
#include <hip/hip_runtime.h>
#include <math.h>

// BiometricLSTM: 2-layer LSTM, B=512, T=2048, I=3, H=64, fp32 in/out. Output = final h2 (B,64).
//
// R8: R6/R7 identical perf (VGPR 120 both, AGPR-resident weights free on gfx950
// unified file) killed the AGPR-overhead theory. Instruction economics say the
// binding pipe is LDS issue: ~264 broadcast ds_read_b128 + ~50 b32 per CU-iter
// ~= 2400 cyc ~= observed 2642 cyc/iter. Fix: h state stored in LDS as f16 and
// dots done with v_dot2_f32_f16 (2 MACs/instr, f32 accumulate):
//   - h1/h2 reads: 16+16 b128 -> 8+8 b128 per thread-iter
//   - 192 fmaf -> 96 fdot2 per thread-iter (VALU halved too)
//   - weights pre-packed half2 once (96 regs, was 192)
// c-state, gates, x, and all accumulation remain fp32. Structure unchanged from
// R6: 512 blocks x 256 threads (4 waves), 1 seq/block, 2 blocks/CU, 2-barrier
// software-pipelined layers (L0 step it, L1 step it-1).

typedef _Float16 half2_t __attribute__((ext_vector_type(2)));

constexpr int TT = 2048;

__device__ __forceinline__ float fast_sigmoid(float x) {
    return 1.0f / (1.0f + __expf(-x));
}

// overflow-safe tanh: c can reach O(100s); exp(-2|x|) underflows harmlessly to 0 -> +/-1
__device__ __forceinline__ float fast_tanh(float x) {
    float ax = fabsf(x);
    float t  = __expf(-2.0f * ax);
    return copysignf((1.0f - t) / (1.0f + t), x);
}

// f32 += f16*f16 + f16*f16 (v_dot2_f32_f16); fallback keeps the LDS win if absent
__device__ __forceinline__ float dot2acc(half2_t a, half2_t b, float c) {
#if __has_builtin(__builtin_amdgcn_fdot2)
    return __builtin_amdgcn_fdot2(a, b, c, false);
#else
    c = fmaf((float)a[0], (float)b[0], c);
    return fmaf((float)a[1], (float)b[1], c);
#endif
}

__global__ __launch_bounds__(256) void lstm2_fused(
    const float* __restrict__ x,
    const float* __restrict__ Wih0, const float* __restrict__ Whh0,
    const float* __restrict__ bih0, const float* __restrict__ bhh0,
    const float* __restrict__ Wih1, const float* __restrict__ Whh1,
    const float* __restrict__ bih1, const float* __restrict__ bhh1,
    float* __restrict__ out)
{
    // x stride-4 (one ds_read_b128/iter); +4 tail for the unconditional it==TT read
    __shared__ __align__(16) float    xs4[TT * 4 + 4];   // 32 KB
    __shared__ __align__(16) _Float16 h1buf[2][64];      // [parity][k], f16, 128 B each
    __shared__ __align__(16) _Float16 h2buf[2][64];
    __shared__ __align__(16) float    gbuf[2][256];      // [layer][gate], activated, f32

    const int j = threadIdx.x;            // gate index 0..255

    // ---- preload x: global (T,3) packed -> LDS stride 4 (w-slot unused) ----
    {
        const float* xg = x + (size_t)blockIdx.x * (TT * 3);
        for (int idx = j; idx < TT * 3; idx += 256) {
            int t = idx / 3;              // magic-mul, no HW divide
            int c = idx - 3 * t;
            xs4[t * 4 + c] = xg[idx];
        }
        if (j < 4) xs4[TT * 4 + j] = 0.0f;
    }
    // ---- zero h double-buffers (2*128 halves) ----
    if (j < 128)       ((_Float16*)h1buf)[j] = (_Float16)0.0f;
    else               ((_Float16*)h2buf)[j - 128] = (_Float16)0.0f;

    // ---- thread j's weights, packed half2: gate j of both layers (96 regs) ----
    half2_t wA[32], wB[32], wC[32];   // Whh0 row j | Wih1 row j | Whh1 row j
    {
        const float4* a = (const float4*)(Whh0 + j * 64);
        const float4* b = (const float4*)(Wih1 + j * 64);
        const float4* c = (const float4*)(Whh1 + j * 64);
        #pragma unroll
        for (int k = 0; k < 16; ++k) {
            float4 va = a[k];
            wA[2*k+0] = half2_t{(_Float16)va.x, (_Float16)va.y};
            wA[2*k+1] = half2_t{(_Float16)va.z, (_Float16)va.w};
            float4 vb = b[k];
            wB[2*k+0] = half2_t{(_Float16)vb.x, (_Float16)vb.y};
            wB[2*k+1] = half2_t{(_Float16)vb.z, (_Float16)vb.w};
            float4 vc = c[k];
            wC[2*k+0] = half2_t{(_Float16)vc.x, (_Float16)vc.y};
            wC[2*k+1] = half2_t{(_Float16)vc.z, (_Float16)vc.w};
        }
    }
    const float wx0 = Wih0[j*3+0], wx1 = Wih0[j*3+1], wx2 = Wih0[j*3+2];
    const float bias0 = bih0[j] + bhh0[j];
    const float bias1 = bih1[j] + bhh1[j];

    const int cls = j >> 6;               // 0:i 1:f 2:g 3:o (== wave index, uniform)
    const int uL  = (j >> 6) & 1;         // phase-2: wave0 -> L0, wave1 -> L1
    const int uj  = j & 63;
    float c_state = 0.0f;

    __syncthreads();

    // iter it: L0 computes step it (valid it<TT); L1 computes step it-1 (valid it>=1).
    // Edge iters compute garbage unconditionally on zeroed/in-bounds inputs; only
    // state updates / stores are guarded.
    for (int it = 0; it <= TT; ++it) {
        const int cur  = it & 1;
        const int prev = cur ^ 1;

        // ---------------- phase 1: gate dot-products (f16 x f16 -> f32) ----------------
        const float4* h1p = (const float4*)h1buf[prev];   // h1[it-1], 8 halves per float4
        const float4* h2p = (const float4*)h2buf[cur];    // h2[it-2]

        float Aa=0.f, Ab=0.f;   // L0:  Whh0[j] . h1
        float Ia=0.f, Ib=0.f;   // L1:  Wih1[j] . h1
        float Ha=0.f, Hb=0.f;   // L1:  Whh1[j] . h2
        #pragma unroll
        for (int k = 0; k < 8; ++k) {
            float4 p = h1p[k];
            float4 r = h2p[k];
            half2_t p0 = __builtin_bit_cast(half2_t, p.x);
            half2_t p1 = __builtin_bit_cast(half2_t, p.y);
            half2_t p2 = __builtin_bit_cast(half2_t, p.z);
            half2_t p3 = __builtin_bit_cast(half2_t, p.w);
            half2_t r0 = __builtin_bit_cast(half2_t, r.x);
            half2_t r1 = __builtin_bit_cast(half2_t, r.y);
            half2_t r2 = __builtin_bit_cast(half2_t, r.z);
            half2_t r3 = __builtin_bit_cast(half2_t, r.w);
            Aa = dot2acc(p0, wA[4*k+0], Aa); Ab = dot2acc(p1, wA[4*k+1], Ab);
            Aa = dot2acc(p2, wA[4*k+2], Aa); Ab = dot2acc(p3, wA[4*k+3], Ab);
            Ia = dot2acc(p0, wB[4*k+0], Ia); Ib = dot2acc(p1, wB[4*k+1], Ib);
            Ia = dot2acc(p2, wB[4*k+2], Ia); Ib = dot2acc(p3, wB[4*k+3], Ib);
            Ha = dot2acc(r0, wC[4*k+0], Ha); Hb = dot2acc(r1, wC[4*k+1], Hb);
            Ha = dot2acc(r2, wC[4*k+2], Ha); Hb = dot2acc(r3, wC[4*k+3], Hb);
        }
        float4 xv = ((const float4*)xs4)[it];
        float g0 = bias0 + (Aa + Ab) + wx0*xv.x + wx1*xv.y + wx2*xv.z;
        float g1 = bias1 + (Ia + Ib) + (Ha + Hb);
        if (cls == 2) { g0 = fast_tanh(g0);    g1 = fast_tanh(g1); }
        else          { g0 = fast_sigmoid(g0); g1 = fast_sigmoid(g1); }
        gbuf[0][j] = g0;
        gbuf[1][j] = g1;
        __syncthreads();

        // ---------------- phase 2: state updates (threads 0-127) ----------------
        if (j < 128) {
            if (uL == 0) {
                if (it < TT) {
                    float iv = gbuf[0][      uj];
                    float fv = gbuf[0][ 64 + uj];
                    float gv = gbuf[0][128 + uj];
                    float ov = gbuf[0][192 + uj];
                    c_state = fmaf(fv, c_state, iv * gv);
                    h1buf[cur][uj] = (_Float16)(ov * fast_tanh(c_state));   // h1[it]
                }
            } else {
                if (it >= 1) {
                    float iv = gbuf[1][      uj];
                    float fv = gbuf[1][ 64 + uj];
                    float gv = gbuf[1][128 + uj];
                    float ov = gbuf[1][192 + uj];
                    c_state = fmaf(fv, c_state, iv * gv);
                    float hv = ov * fast_tanh(c_state);
                    h2buf[prev][uj] = (_Float16)hv;                         // h2[it-1]
                    if (it == TT)
                        out[(size_t)blockIdx.x * 64 + uj] = hv;             // f32 output
                }
            }
        }
        __syncthreads();
    }
}

extern "C" void kernel_launch(void* const* d_in, const int* in_sizes, int n_in,
                              void* d_out, int out_size, void* d_ws, size_t ws_size,
                              hipStream_t stream) {
    const float* x    = (const float*)d_in[0];
    const float* Wih0 = (const float*)d_in[1];
    const float* Whh0 = (const float*)d_in[2];
    const float* bih0 = (const float*)d_in[3];
    const float* bhh0 = (const float*)d_in[4];
    const float* Wih1 = (const float*)d_in[5];
    const float* Whh1 = (const float*)d_in[6];
    const float* bih1 = (const float*)d_in[7];
    const float* bhh1 = (const float*)d_in[8];
    float* out = (float*)d_out;

    // 512 sequences, 1 per block -> 512 blocks = 2 blocks/CU (2 waves/SIMD);
    // 256 threads (4 waves).
    lstm2_fused<<<512, 256, 0, stream>>>(x, Wih0, Whh0, bih0, bhh0,
                                         Wih1, Whh1, bih1, bhh1, out);
}